// Round 4
// baseline (163.909 us; speedup 1.0000x reference)
//
#include <hip/hip_runtime.h>
#include <stdint.h>

// LearnedTripleConnect: B=8,N=8192,S=8,D=64. out[b,n] = mean_s( gelu([xi|xj|xk]W1+b1) ) W2 + b2
// Round 4: LDS staging with line-coalesced gather (8 lanes = 1 row = 2 cache lines),
// source-side XOR swizzle -> conflict-free ds_read_b128, 1 barrier/tile (deferred GEMM2),
// 3 blocks/CU.

#define NT   4            // 64-token tiles per block
#define NBLK 2048         // 2048*4*64 = 524288 tokens

typedef short  short8 __attribute__((ext_vector_type(8)));
typedef float  f32x4  __attribute__((ext_vector_type(4)));
typedef float  f32x16 __attribute__((ext_vector_type(16)));

__device__ __forceinline__ unsigned short f2bf(float f){
  union { float f; unsigned u; } a; a.f = f;
  unsigned u = a.u;
  u += 0x7fffu + ((u >> 16) & 1u);   // RNE
  return (unsigned short)(u >> 16);
}
__device__ __forceinline__ float fast_gelu(float x){
  // x * sigmoid(1.5957691*(x + 0.044715 x^3)) via exp2; |err vs exact gelu| ~3e-4
  float x2 = x * x;
  float t  = __builtin_fmaf(x2, -0.1029437f, -2.3022083f);
  float p  = __builtin_amdgcn_exp2f(x * t);
  return x * __builtin_amdgcn_rcpf(1.0f + p);
}

// ---------------- fused prep ----------------
__global__ void prep_kernel(const float* __restrict__ x, const float* __restrict__ W1,
                            const float* __restrict__ W2, short* __restrict__ xb,
                            short* __restrict__ w1f, short* __restrict__ w2f){
  int bid = blockIdx.x;
  if (bid < 2048){
    long i = (long)bid * 256 + threadIdx.x;   // 0..524287, 8 elems each
    const float4* p = (const float4*)(x + i * 8);
    float4 a = p[0], b = p[1];
    short8 v;
    v[0]=(short)f2bf(a.x); v[1]=(short)f2bf(a.y); v[2]=(short)f2bf(a.z); v[3]=(short)f2bf(a.w);
    v[4]=(short)f2bf(b.x); v[5]=(short)f2bf(b.y); v[6]=(short)f2bf(b.z); v[7]=(short)f2bf(b.w);
    *(short8*)(xb + i * 8) = v;
  } else if (threadIdx.x < 64){
    int f = bid - 2048, lane = threadIdx.x;
    short8 v;
    if (f < 48){
      int cb = f / 12, t = f % 12;
      #pragma unroll
      for (int j = 0; j < 8; j++)
        v[j] = (short)f2bf(W1[(t*16 + 8*(lane>>5) + j)*128 + cb*32 + (lane&31)]);
      *(short8*)(w1f + ((long)(f*64 + lane))*8) = v;
    } else {
      int g = f - 48; int w = g >> 2, q = g & 3;
      #pragma unroll
      for (int j = 0; j < 8; j++)
        v[j] = (short)f2bf(W2[(q*32 + 8*(lane>>4) + j)*64 + w*16 + (lane&15)]);
      *(short8*)(w2f + ((long)(g*64 + lane))*8) = v;
    }
  }
}

// ---------------- main kernel ----------------
// Per-tile LDS buffer (17 KB): own 8 rows (1 KB) | j 64 rows (8 KB) | k 64 rows (8 KB).
// Row r stored swizzled: chunk c (16B) lives at slot c^(r&7). Staged by 17 wave-instructions,
// each covering whole rows (2 cache lines/row -> 16 TA transactions/instr).
__global__ __launch_bounds__(512, 6) void ltc_main(
    const short* __restrict__ xb,  const short* __restrict__ w1f,
    const short* __restrict__ w2f, const int* __restrict__ jidx,
    const int* __restrict__ kidx,  const float* __restrict__ b1,
    const float* __restrict__ b2,  float* __restrict__ out)
{
  __shared__ short Ab[2][8704];     // 2 x 17 KB
  __shared__ short HB[2][16 * 136]; // hbar ping-pong: 8 valid rows x 128 h, stride 136

  const int tid  = threadIdx.x;
  const int w    = tid >> 6, lane = tid & 63;
  const int cb   = w & 3,  rb  = w >> 2;
  const int l31  = lane & 31, hi = lane >> 5;
  const int l15  = lane & 15, q4 = lane >> 4;

  // resident weight fragments
  short8 w1v[12];
  #pragma unroll
  for (int t = 0; t < 12; t++)
    w1v[t] = *(const short8*)(w1f + ((long)((cb * 12 + t) * 64 + lane)) * 8);
  short8 w2v[4];
  #pragma unroll
  for (int q = 0; q < 4; q++)
    w2v[q] = *(const short8*)(w2f + ((long)((cb * 4 + q) * 64 + lane)) * 8);

  float b1v = b1[cb * 32 + l31];
  float b2v = b2[cb * 16 + l15];

  // zero HB rows 8-15 of both buffers (GEMM2 A-frag garbage rows; results discarded)
  for (int i = tid; i < 8 * 136; i += 512){ HB[0][8*136 + i] = 0; HB[1][8*136 + i] = 0; }

  const int bid   = blockIdx.x;
  const int batch = bid & 7;
  const int T0    = batch * 1024 + (bid >> 3) * NT;   // batch-affine XCD swizzle
  const long tb0  = (long)T0 * 64;
  const int bbase = batch << 13;                      // batch row base (b*8192)

  // stage-lane roles: 8 lanes fetch one whole row, source chunk pre-swizzled
  const int t_lo = w * 8 + (lane >> 3);               // tile-local token this lane serves
  const int csw  = (lane & 7) ^ ((lane >> 3) & 7);    // swizzled chunk index

  // ds-read byte offsets for the 12 A-frags (swizzle applied)
  const int r_own = rb * 4 + (l31 >> 3);
  const int tok   = rb * 32 + l31;
  int offA[12];
  #pragma unroll
  for (int t2 = 0; t2 < 4; t2++){
    offA[t2]     = r_own * 128 + (((2*t2 + hi) ^ r_own) << 4);
    offA[4 + t2] = 1024 + tok * 128 + (((2*t2 + hi) ^ (tok & 7)) << 4);
    offA[8 + t2] = 9216 + tok * 128 + (((2*t2 + hi) ^ (tok & 7)) << 4);
  }

  auto stage = [&](int buf, long tb, int jn, int kn){
    const short* gj = xb + (long)(bbase + jn) * 64 + csw * 8;
    __builtin_amdgcn_global_load_lds(
        (const __attribute__((address_space(1))) unsigned int*)gj,
        (__attribute__((address_space(3))) unsigned int*)(&Ab[buf][512 + w * 512]), 16, 0, 0);
    const short* gk = xb + (long)(bbase + kn) * 64 + csw * 8;
    __builtin_amdgcn_global_load_lds(
        (const __attribute__((address_space(1))) unsigned int*)gk,
        (__attribute__((address_space(3))) unsigned int*)(&Ab[buf][4608 + w * 512]), 16, 0, 0);
    if (w == 0){
      const short* go = xb + (long)((int)(tb >> 3) + (lane >> 3)) * 64 + csw * 8;
      __builtin_amdgcn_global_load_lds(
          (const __attribute__((address_space(1))) unsigned int*)go,
          (__attribute__((address_space(3))) unsigned int*)(&Ab[buf][0]), 16, 0, 0);
    }
  };

  auto gemm2_store = [&](int buf, int ttp){
    f32x4 acc2 = {0.f, 0.f, 0.f, 0.f};
    #pragma unroll
    for (int q = 0; q < 4; q++){
      short8 hbf = *(const short8*)&HB[buf][l15 * 136 + q * 32 + q4 * 8];
      acc2 = __builtin_amdgcn_mfma_f32_16x16x32_bf16(hbf, w2v[q], acc2, 0, 0, 0);
    }
    if (lane < 32){                       // rows 0-7 valid
      long G = ((long)(T0 + ttp)) * 8;
      #pragma unroll
      for (int r = 0; r < 4; r++)
        out[(G + 4 * q4 + r) * 64 + cb * 16 + l15] = acc2[r] + b2v;
    }
  };

  // prologue
  int jn0 = jidx[tb0 + t_lo], kn0 = kidx[tb0 + t_lo];
  stage(0, tb0, jn0, kn0);
  int jnS = 0, knS = 0;
  if (NT > 1){ jnS = jidx[tb0 + 64 + t_lo]; knS = kidx[tb0 + 64 + t_lo]; }

  for (int tt = 0; tt < NT; ++tt){
    const int cur = tt & 1;
    asm volatile("s_waitcnt vmcnt(0) lgkmcnt(0)\n\ts_barrier" ::: "memory");  // Ab[cur]+HB[cur^1] ready
    if (tt + 1 < NT) stage(cur ^ 1, tb0 + (long)(tt + 1) * 64, jnS, knS);
    if (tt + 2 < NT){
      jnS = jidx[tb0 + (long)(tt + 2) * 64 + t_lo];
      knS = kidx[tb0 + (long)(tt + 2) * 64 + t_lo];
    }

    // deferred GEMM2 of previous tile (HB published by this tile's top barrier)
    if (tt > 0 && w < 4) gemm2_store(cur ^ 1, tt - 1);

    // GEMM1: C[32 tok][32 h], C-init = b1
    const char* Abase = (const char*)&Ab[cur][0];
    f32x16 acc;
    #pragma unroll
    for (int r = 0; r < 16; r++) acc[r] = b1v;
    #pragma unroll
    for (int t = 0; t < 12; t++){
      short8 af = *(const short8*)(Abase + offA[t]);
      acc = __builtin_amdgcn_mfma_f32_32x32x16_bf16(af, w1v[t], acc, 0, 0, 0);
    }

    // GELU + s-reduce: token row=(reg&3)+8*(reg>>2)+4*hi -> group o=reg>>2, s=(reg&3)+4*hi
    #pragma unroll
    for (int o = 0; o < 4; o++){
      float s0 = fast_gelu(acc[4*o+0]);
      s0 += fast_gelu(acc[4*o+1]);
      s0 += fast_gelu(acc[4*o+2]);
      s0 += fast_gelu(acc[4*o+3]);
      float other = __shfl_xor(s0, 32);
      float hbv = (s0 + other) * 0.125f;
      if (hi == 0)
        HB[cur][(rb * 4 + o) * 136 + cb * 32 + l31] = (short)f2bf(hbv);
    }
  }

  // epilogue: last tile's GEMM2
  asm volatile("s_waitcnt lgkmcnt(0)\n\ts_barrier" ::: "memory");
  if (w < 4) gemm2_store((NT - 1) & 1, NT - 1);
}

// ---------------- fallback (ws too small): correct, slow ----------------
__global__ void ltc_naive(const float* __restrict__ x, const int* __restrict__ jidx,
                          const int* __restrict__ kidx, const float* __restrict__ W1,
                          const float* __restrict__ b1, const float* __restrict__ W2,
                          const float* __restrict__ b2, float* __restrict__ out)
{
  int gidx = blockIdx.x;            // b*8192+n
  int b = gidx >> 13;
  __shared__ float trip[8][192];
  __shared__ float hb[128];
  int t = threadIdx.x;              // 128
  for (int i = t; i < 8 * 192; i += 128){
    int s = i / 192, c = i - s * 192;
    int v = c >> 6, cc = c & 63;
    int src;
    if (v == 0)      src = gidx & 8191;
    else if (v == 1) src = jidx[gidx * 8 + s];
    else             src = kidx[gidx * 8 + s];
    trip[s][c] = x[((long)(b << 13) + src) * 64 + cc];
  }
  __syncthreads();
  float z[8];
  #pragma unroll
  for (int s = 0; s < 8; s++) z[s] = b1[t];
  for (int k = 0; k < 192; k++){
    float wv = W1[k * 128 + t];
    #pragma unroll
    for (int s = 0; s < 8; s++) z[s] = fmaf(trip[s][k], wv, z[s]);
  }
  float acc = 0.f;
  #pragma unroll
  for (int s = 0; s < 8; s++) acc += fast_gelu(z[s]);
  hb[t] = acc * 0.125f;
  __syncthreads();
  if (t < 64){
    float o = b2[t];
    for (int h = 0; h < 128; h++) o = fmaf(hb[h], W2[h * 64 + t], o);
    out[(long)gidx * 64 + t] = o;
  }
}

extern "C" void kernel_launch(void* const* d_in, const int* in_sizes, int n_in,
                              void* d_out, int out_size, void* d_ws, size_t ws_size,
                              hipStream_t stream) {
  const float* x   = (const float*)d_in[0];
  const int*   jix = (const int*)  d_in[1];
  const int*   kix = (const int*)  d_in[2];
  const float* W1  = (const float*)d_in[3];
  const float* b1  = (const float*)d_in[4];
  const float* W2  = (const float*)d_in[5];
  const float* b2  = (const float*)d_in[6];
  float* out = (float*)d_out;

  const size_t xb_elems  = (size_t)8 * 8192 * 64;        // 4,194,304 bf16
  const size_t w1f_elems = 48 * 64 * 8;
  const size_t w2f_elems = 16 * 64 * 8;
  const size_t need = (xb_elems + w1f_elems + w2f_elems) * sizeof(short);

  if (ws_size >= need){
    short* xb  = (short*)d_ws;
    short* w1f = xb + xb_elems;
    short* w2f = w1f + w1f_elems;
    prep_kernel<<<2112, 256, 0, stream>>>(x, W1, W2, xb, w1f, w2f);
    ltc_main<<<NBLK, 512, 0, stream>>>(xb, w1f, w2f, jix, kix, b1, b2, out);
  } else {
    ltc_naive<<<8 * 8192, 128, 0, stream>>>(x, jix, kix, W1, b1, W2, b2, out);
  }
}

// Round 5
// 59.682 us; speedup vs baseline: 2.7464x; 2.7464x over previous
//
#include <hip/hip_runtime.h>
#include <stdint.h>

// LearnedTripleConnect: B=8,N=8192,S=8,D=64. out[b,n] = mean_s( gelu([xi|xj|xk]W1+b1) ) W2 + b2
// Round 5: round-4 structure (coalesced row gather + source-swizzle + 1 barrier/tile)
// with launch_bounds(512,4) to eliminate the round-4 scratch spill (VGPR 40 + 500MB scratch).

#define NT   4            // 64-token tiles per block
#define NBLK 2048         // 2048*4*64 = 524288 tokens

typedef short  short8 __attribute__((ext_vector_type(8)));
typedef float  f32x4  __attribute__((ext_vector_type(4)));
typedef float  f32x16 __attribute__((ext_vector_type(16)));

__device__ __forceinline__ unsigned short f2bf(float f){
  union { float f; unsigned u; } a; a.f = f;
  unsigned u = a.u;
  u += 0x7fffu + ((u >> 16) & 1u);   // RNE
  return (unsigned short)(u >> 16);
}
__device__ __forceinline__ float fast_gelu(float x){
  // x * sigmoid(1.5957691*(x + 0.044715 x^3)) via exp2; |err vs exact gelu| ~3e-4
  float x2 = x * x;
  float t  = __builtin_fmaf(x2, -0.1029437f, -2.3022083f);
  float p  = __builtin_amdgcn_exp2f(x * t);
  return x * __builtin_amdgcn_rcpf(1.0f + p);
}

// ---------------- fused prep ----------------
__global__ void prep_kernel(const float* __restrict__ x, const float* __restrict__ W1,
                            const float* __restrict__ W2, short* __restrict__ xb,
                            short* __restrict__ w1f, short* __restrict__ w2f){
  int bid = blockIdx.x;
  if (bid < 2048){
    long i = (long)bid * 256 + threadIdx.x;   // 0..524287, 8 elems each
    const float4* p = (const float4*)(x + i * 8);
    float4 a = p[0], b = p[1];
    short8 v;
    v[0]=(short)f2bf(a.x); v[1]=(short)f2bf(a.y); v[2]=(short)f2bf(a.z); v[3]=(short)f2bf(a.w);
    v[4]=(short)f2bf(b.x); v[5]=(short)f2bf(b.y); v[6]=(short)f2bf(b.z); v[7]=(short)f2bf(b.w);
    *(short8*)(xb + i * 8) = v;
  } else if (threadIdx.x < 64){
    int f = bid - 2048, lane = threadIdx.x;
    short8 v;
    if (f < 48){
      int cb = f / 12, t = f % 12;
      #pragma unroll
      for (int j = 0; j < 8; j++)
        v[j] = (short)f2bf(W1[(t*16 + 8*(lane>>5) + j)*128 + cb*32 + (lane&31)]);
      *(short8*)(w1f + ((long)(f*64 + lane))*8) = v;
    } else {
      int g = f - 48; int w = g >> 2, q = g & 3;
      #pragma unroll
      for (int j = 0; j < 8; j++)
        v[j] = (short)f2bf(W2[(q*32 + 8*(lane>>4) + j)*64 + w*16 + (lane&15)]);
      *(short8*)(w2f + ((long)(g*64 + lane))*8) = v;
    }
  }
}

// ---------------- main kernel ----------------
// Per-tile LDS buffer (17 KB): own 8 rows (1 KB) | j 64 rows (8 KB) | k 64 rows (8 KB).
// Row r stored swizzled: chunk c (16B) lives at slot c^(r&7). Staged by 17 wave-instructions,
// each covering whole rows (8 rows x 2 cache lines -> 16 line-touches/instr).
__global__ __launch_bounds__(512, 4) void ltc_main(
    const short* __restrict__ xb,  const short* __restrict__ w1f,
    const short* __restrict__ w2f, const int* __restrict__ jidx,
    const int* __restrict__ kidx,  const float* __restrict__ b1,
    const float* __restrict__ b2,  float* __restrict__ out)
{
  __shared__ short Ab[2][8704];     // 2 x 17 KB
  __shared__ short HB[2][16 * 136]; // hbar ping-pong: 8 valid rows x 128 h, stride 136

  const int tid  = threadIdx.x;
  const int w    = tid >> 6, lane = tid & 63;
  const int cb   = w & 3,  rb  = w >> 2;
  const int l31  = lane & 31, hi = lane >> 5;
  const int l15  = lane & 15, q4 = lane >> 4;

  // resident weight fragments
  short8 w1v[12];
  #pragma unroll
  for (int t = 0; t < 12; t++)
    w1v[t] = *(const short8*)(w1f + ((long)((cb * 12 + t) * 64 + lane)) * 8);
  short8 w2v[4];
  #pragma unroll
  for (int q = 0; q < 4; q++)
    w2v[q] = *(const short8*)(w2f + ((long)((cb * 4 + q) * 64 + lane)) * 8);

  float b1v = b1[cb * 32 + l31];
  float b2v = b2[cb * 16 + l15];

  // zero HB rows 8-15 of both buffers (GEMM2 A-frag garbage rows; results discarded)
  for (int i = tid; i < 8 * 136; i += 512){ HB[0][8*136 + i] = 0; HB[1][8*136 + i] = 0; }

  const int bid   = blockIdx.x;
  const int batch = bid & 7;
  const int T0    = batch * 1024 + (bid >> 3) * NT;   // batch-affine XCD swizzle
  const long tb0  = (long)T0 * 64;
  const int bbase = batch << 13;                      // batch row base (b*8192)

  // stage-lane roles: 8 lanes fetch one whole row, source chunk pre-swizzled
  const int t_lo = w * 8 + (lane >> 3);               // tile-local token this lane serves
  const int csw  = (lane & 7) ^ ((lane >> 3) & 7);    // swizzled chunk index

  // ds-read base byte offsets (chunk XOR applied inline per K-step)
  const int r_own  = rb * 4 + (l31 >> 3);
  const int tok    = rb * 32 + l31;
  const int baseO  = r_own * 128;
  const int baseJ  = 1024 + tok * 128;
  const int baseK  = 9216 + tok * 128;
  const int xorO   = r_own & 7;
  const int xorJK  = tok & 7;

  auto stage = [&](int buf, long tb, int jn, int kn){
    const short* gj = xb + (long)(bbase + jn) * 64 + csw * 8;
    __builtin_amdgcn_global_load_lds(
        (const __attribute__((address_space(1))) unsigned int*)gj,
        (__attribute__((address_space(3))) unsigned int*)(&Ab[buf][512 + w * 512]), 16, 0, 0);
    const short* gk = xb + (long)(bbase + kn) * 64 + csw * 8;
    __builtin_amdgcn_global_load_lds(
        (const __attribute__((address_space(1))) unsigned int*)gk,
        (__attribute__((address_space(3))) unsigned int*)(&Ab[buf][4608 + w * 512]), 16, 0, 0);
    if (w == 0){
      const short* go = xb + (long)((int)(tb >> 3) + (lane >> 3)) * 64 + csw * 8;
      __builtin_amdgcn_global_load_lds(
          (const __attribute__((address_space(1))) unsigned int*)go,
          (__attribute__((address_space(3))) unsigned int*)(&Ab[buf][0]), 16, 0, 0);
    }
  };

  auto gemm2_store = [&](int buf, int ttp){
    f32x4 acc2 = {0.f, 0.f, 0.f, 0.f};
    #pragma unroll
    for (int q = 0; q < 4; q++){
      short8 hbf = *(const short8*)&HB[buf][l15 * 136 + q * 32 + q4 * 8];
      acc2 = __builtin_amdgcn_mfma_f32_16x16x32_bf16(hbf, w2v[q], acc2, 0, 0, 0);
    }
    if (lane < 32){                       // rows 0-7 valid
      long G = ((long)(T0 + ttp)) * 8;
      #pragma unroll
      for (int r = 0; r < 4; r++)
        out[(G + 4 * q4 + r) * 64 + cb * 16 + l15] = acc2[r] + b2v;
    }
  };

  // prologue
  int jn0 = jidx[tb0 + t_lo], kn0 = kidx[tb0 + t_lo];
  stage(0, tb0, jn0, kn0);
  int jnS = 0, knS = 0;
  if (NT > 1){ jnS = jidx[tb0 + 64 + t_lo]; knS = kidx[tb0 + 64 + t_lo]; }

  for (int tt = 0; tt < NT; ++tt){
    const int cur = tt & 1;
    asm volatile("s_waitcnt vmcnt(0) lgkmcnt(0)\n\ts_barrier" ::: "memory");  // Ab[cur]+HB[cur^1] ready
    if (tt + 1 < NT) stage(cur ^ 1, tb0 + (long)(tt + 1) * 64, jnS, knS);
    if (tt + 2 < NT){
      jnS = jidx[tb0 + (long)(tt + 2) * 64 + t_lo];
      knS = kidx[tb0 + (long)(tt + 2) * 64 + t_lo];
    }

    // deferred GEMM2 of previous tile (HB published by this tile's top barrier)
    if (tt > 0 && w < 4) gemm2_store(cur ^ 1, tt - 1);

    // GEMM1: C[32 tok][32 h], C-init = b1
    const char* Abase = (const char*)&Ab[cur][0];
    f32x16 acc;
    #pragma unroll
    for (int r = 0; r < 16; r++) acc[r] = b1v;
    #pragma unroll
    for (int t = 0; t < 12; t++){
      int off;
      if (t < 4)       off = baseO + (((2*t + hi)     ^ xorO ) << 4);
      else if (t < 8)  off = baseJ + (((2*(t-4) + hi) ^ xorJK) << 4);
      else             off = baseK + (((2*(t-8) + hi) ^ xorJK) << 4);
      short8 af = *(const short8*)(Abase + off);
      acc = __builtin_amdgcn_mfma_f32_32x32x16_bf16(af, w1v[t], acc, 0, 0, 0);
    }

    // GELU + s-reduce: token row=(reg&3)+8*(reg>>2)+4*hi -> group o=reg>>2, s=(reg&3)+4*hi
    #pragma unroll
    for (int o = 0; o < 4; o++){
      float s0 = fast_gelu(acc[4*o+0]);
      s0 += fast_gelu(acc[4*o+1]);
      s0 += fast_gelu(acc[4*o+2]);
      s0 += fast_gelu(acc[4*o+3]);
      float other = __shfl_xor(s0, 32);
      float hbv = (s0 + other) * 0.125f;
      if (hi == 0)
        HB[cur][(rb * 4 + o) * 136 + cb * 32 + l31] = (short)f2bf(hbv);
    }
  }

  // epilogue: last tile's GEMM2
  asm volatile("s_waitcnt lgkmcnt(0)\n\ts_barrier" ::: "memory");
  if (w < 4) gemm2_store((NT - 1) & 1, NT - 1);
}

// ---------------- fallback (ws too small): correct, slow ----------------
__global__ void ltc_naive(const float* __restrict__ x, const int* __restrict__ jidx,
                          const int* __restrict__ kidx, const float* __restrict__ W1,
                          const float* __restrict__ b1, const float* __restrict__ W2,
                          const float* __restrict__ b2, float* __restrict__ out)
{
  int gidx = blockIdx.x;            // b*8192+n
  int b = gidx >> 13;
  __shared__ float trip[8][192];
  __shared__ float hb[128];
  int t = threadIdx.x;              // 128
  for (int i = t; i < 8 * 192; i += 128){
    int s = i / 192, c = i - s * 192;
    int v = c >> 6, cc = c & 63;
    int src;
    if (v == 0)      src = gidx & 8191;
    else if (v == 1) src = jidx[gidx * 8 + s];
    else             src = kidx[gidx * 8 + s];
    trip[s][c] = x[((long)(b << 13) + src) * 64 + cc];
  }
  __syncthreads();
  float z[8];
  #pragma unroll
  for (int s = 0; s < 8; s++) z[s] = b1[t];
  for (int k = 0; k < 192; k++){
    float wv = W1[k * 128 + t];
    #pragma unroll
    for (int s = 0; s < 8; s++) z[s] = fmaf(trip[s][k], wv, z[s]);
  }
  float acc = 0.f;
  #pragma unroll
  for (int s = 0; s < 8; s++) acc += fast_gelu(z[s]);
  hb[t] = acc * 0.125f;
  __syncthreads();
  if (t < 64){
    float o = b2[t];
    for (int h = 0; h < 128; h++) o = fmaf(hb[h], W2[h * 64 + t], o);
    out[(long)gidx * 64 + t] = o;
  }
}

extern "C" void kernel_launch(void* const* d_in, const int* in_sizes, int n_in,
                              void* d_out, int out_size, void* d_ws, size_t ws_size,
                              hipStream_t stream) {
  const float* x   = (const float*)d_in[0];
  const int*   jix = (const int*)  d_in[1];
  const int*   kix = (const int*)  d_in[2];
  const float* W1  = (const float*)d_in[3];
  const float* b1  = (const float*)d_in[4];
  const float* W2  = (const float*)d_in[5];
  const float* b2  = (const float*)d_in[6];
  float* out = (float*)d_out;

  const size_t xb_elems  = (size_t)8 * 8192 * 64;        // 4,194,304 bf16
  const size_t w1f_elems = 48 * 64 * 8;
  const size_t w2f_elems = 16 * 64 * 8;
  const size_t need = (xb_elems + w1f_elems + w2f_elems) * sizeof(short);

  if (ws_size >= need){
    short* xb  = (short*)d_ws;
    short* w1f = xb + xb_elems;
    short* w2f = w1f + w1f_elems;
    prep_kernel<<<2112, 256, 0, stream>>>(x, W1, W2, xb, w1f, w2f);
    ltc_main<<<NBLK, 512, 0, stream>>>(xb, w1f, w2f, jix, kix, b1, b2, out);
  } else {
    ltc_naive<<<8 * 8192, 128, 0, stream>>>(x, jix, kix, W1, b1, W2, b2, out);
  }
}